// Round 1
// baseline (252.125 us; speedup 1.0000x reference)
//
#include <hip/hip_runtime.h>
#include <hip/hip_bf16.h>

// ---- constants for this problem ----
#define B_NUM 2
#define T_LEN 2048
#define D_DIM 1024
#define H_NUM 16
#define HD_DIM 64

using bf16x8 = __attribute__((ext_vector_type(8))) short;
using f32x4  = __attribute__((ext_vector_type(4))) float;
using u16x4  = __attribute__((ext_vector_type(4))) unsigned short;

__device__ __forceinline__ unsigned short f2bf(float f) {
    union { float f; unsigned u; } v; v.f = f;
    unsigned u = v.u;
    unsigned r = (u + 0x7fffu + ((u >> 16) & 1u)) >> 16;
    return (unsigned short)r;
}

// ---------------- convert fp32 -> bf16 (x + 4 weights) ----------------
__global__ __launch_bounds__(256) void cvt5(
    const float* __restrict__ s0, const float* __restrict__ s1, const float* __restrict__ s2,
    const float* __restrict__ s3, const float* __restrict__ s4,
    unsigned short* __restrict__ d0, unsigned short* __restrict__ d1, unsigned short* __restrict__ d2,
    unsigned short* __restrict__ d3, unsigned short* __restrict__ d4,
    int c0, int c1, int c2, int c3, int c4)
{
    const float* src; unsigned short* dst; int cnt;
    switch (blockIdx.z) {
        case 0: src = s0; dst = d0; cnt = c0; break;
        case 1: src = s1; dst = d1; cnt = c1; break;
        case 2: src = s2; dst = d2; cnt = c2; break;
        case 3: src = s3; dst = d3; cnt = c3; break;
        default: src = s4; dst = d4; cnt = c4; break;
    }
    int i = (blockIdx.x * 256 + threadIdx.x) * 4;
    if (i >= cnt) return;
    float4 v = *(const float4*)(src + i);
    u16x4 o = { f2bf(v.x), f2bf(v.y), f2bf(v.z), f2bf(v.w) };
    *(u16x4*)(dst + i) = o;
}

// ---------------- GEMM core: Y = A[M,K] @ W[N,K]^T, wave computes 64x64 ----------------
// A-frag: lane holds row (lane&15), k = 8*(lane>>4)+i (contiguous 8 bf16)
// B-frag: lane holds col (lane&15) = W row, same k slice
// C/D:    col = lane&15, row = (lane>>4)*4 + reg   [verified m89/m91]
__device__ __forceinline__ void gemm_core(
    const unsigned short* __restrict__ A, const unsigned short* __restrict__ W,
    int m0, int n0, int K, int lane, f32x4 acc[4][4])
{
    const int g = lane >> 4, c = lane & 15;
    #pragma unroll
    for (int mi = 0; mi < 4; ++mi)
        #pragma unroll
        for (int ni = 0; ni < 4; ++ni)
            acc[mi][ni] = (f32x4){0.f, 0.f, 0.f, 0.f};

    #pragma unroll 2
    for (int k0 = 0; k0 < K; k0 += 32) {
        bf16x8 a[4], b[4];
        #pragma unroll
        for (int mi = 0; mi < 4; ++mi)
            a[mi] = *(const bf16x8*)(A + (size_t)(m0 + mi*16 + c) * K + k0 + g*8);
        #pragma unroll
        for (int ni = 0; ni < 4; ++ni)
            b[ni] = *(const bf16x8*)(W + (size_t)(n0 + ni*16 + c) * K + k0 + g*8);
        #pragma unroll
        for (int mi = 0; mi < 4; ++mi)
            #pragma unroll
            for (int ni = 0; ni < 4; ++ni)
                acc[mi][ni] = __builtin_amdgcn_mfma_f32_16x16x32_bf16(a[mi], b[ni], acc[mi][ni], 0, 0, 0);
    }
}

// QKV projection: writes bf16 into [B,H,T,HD] layout; grid.z selects q/k/v
__global__ __launch_bounds__(256) void gemm_qkv(
    const unsigned short* __restrict__ A,
    const unsigned short* __restrict__ Wq, const unsigned short* __restrict__ Wk, const unsigned short* __restrict__ Wv,
    const float* __restrict__ bq, const float* __restrict__ bk, const float* __restrict__ bv,
    unsigned short* __restrict__ Oq, unsigned short* __restrict__ Ok, unsigned short* __restrict__ Ov)
{
    const unsigned short* W; const float* bias; unsigned short* Ob;
    if (blockIdx.z == 0)      { W = Wq; bias = bq; Ob = Oq; }
    else if (blockIdx.z == 1) { W = Wk; bias = bk; Ob = Ok; }
    else                      { W = Wv; bias = bv; Ob = Ov; }
    const int lane = threadIdx.x & 63;
    const int wave = threadIdx.x >> 6;
    const int m0 = blockIdx.x * 128 + (wave >> 1) * 64;
    const int n0 = blockIdx.y * 128 + (wave & 1) * 64;
    f32x4 acc[4][4];
    gemm_core(A, W, m0, n0, D_DIM, lane, acc);
    const int g = lane >> 4, c = lane & 15;
    #pragma unroll
    for (int mi = 0; mi < 4; ++mi) {
        #pragma unroll
        for (int ni = 0; ni < 4; ++ni) {
            const int col = n0 + ni*16 + c;
            const int h = col >> 6, hd = col & 63;
            const float bb = bias[col];
            #pragma unroll
            for (int r = 0; r < 4; ++r) {
                const int row = m0 + mi*16 + g*4 + r;
                const int b_ = row >> 11;          // /T_LEN
                const int t  = row & (T_LEN - 1);
                Ob[((size_t)((b_*H_NUM + h)*T_LEN + t))*HD_DIM + hd] = f2bf(acc[mi][ni][r] + bb);
            }
        }
    }
}

// Output projection: fp32 result to d_out
__global__ __launch_bounds__(256) void gemm_out(
    const unsigned short* __restrict__ A, const unsigned short* __restrict__ W,
    const float* __restrict__ bias, float* __restrict__ Out)
{
    const int lane = threadIdx.x & 63;
    const int wave = threadIdx.x >> 6;
    const int m0 = blockIdx.x * 128 + (wave >> 1) * 64;
    const int n0 = blockIdx.y * 128 + (wave & 1) * 64;
    f32x4 acc[4][4];
    gemm_core(A, W, m0, n0, D_DIM, lane, acc);
    const int g = lane >> 4, c = lane & 15;
    #pragma unroll
    for (int mi = 0; mi < 4; ++mi) {
        #pragma unroll
        for (int ni = 0; ni < 4; ++ni) {
            const int col = n0 + ni*16 + c;
            const float bb = bias[col];
            #pragma unroll
            for (int r = 0; r < 4; ++r) {
                const int row = m0 + mi*16 + g*4 + r;
                Out[(size_t)row * D_DIM + col] = acc[mi][ni][r] + bb;
            }
        }
    }
}

// ---------------- flash attention: 1 wave per (bh, 16-row q tile), KVBLK=32 ----------------
__global__ __launch_bounds__(64) void attn(
    const unsigned short* __restrict__ Q, const unsigned short* __restrict__ K,
    const unsigned short* __restrict__ V, unsigned short* __restrict__ O)
{
    __shared__ __align__(16) unsigned short pl[16 * 40];   // 16 q rows x 32 s, padded to 40
    const int lane = threadIdx.x;
    const int g = lane >> 4, c = lane & 15;
    const int bh = blockIdx.x;               // 0..31
    const int q0 = blockIdx.y * 16;
    const unsigned short* Qb = Q + (size_t)bh * T_LEN * HD_DIM;
    const unsigned short* Kb = K + (size_t)bh * T_LEN * HD_DIM;
    const unsigned short* Vb = V + (size_t)bh * T_LEN * HD_DIM;

    bf16x8 qf[2];
    #pragma unroll
    for (int kk = 0; kk < 2; ++kk)
        qf[kk] = *(const bf16x8*)(Qb + (size_t)(q0 + c) * HD_DIM + kk*32 + g*8);

    f32x4 acc[4];
    #pragma unroll
    for (int ni = 0; ni < 4; ++ni) acc[ni] = (f32x4){0.f, 0.f, 0.f, 0.f};
    float m4[4], l4[4];
    #pragma unroll
    for (int r = 0; r < 4; ++r) { m4[r] = -1e30f; l4[r] = 0.f; }

    const int kv_last = q0 + 15;
    for (int kv0 = 0; kv0 <= kv_last; kv0 += 32) {
        // S = Q K^T  (two 16-wide s-subtiles)
        f32x4 sf[2];
        #pragma unroll
        for (int st = 0; st < 2; ++st) {
            f32x4 s = (f32x4){0.f, 0.f, 0.f, 0.f};
            #pragma unroll
            for (int kk = 0; kk < 2; ++kk) {
                bf16x8 kf = *(const bf16x8*)(Kb + (size_t)(kv0 + st*16 + c) * HD_DIM + kk*32 + g*8);
                s = __builtin_amdgcn_mfma_f32_16x16x32_bf16(qf[kk], kf, s, 0, 0, 0);
            }
            sf[st] = s;
        }
        // scale + causal mask (C layout: row q = g*4+r, col s = st*16+c)
        #pragma unroll
        for (int st = 0; st < 2; ++st) {
            const int sg = kv0 + st*16 + c;
            #pragma unroll
            for (int r = 0; r < 4; ++r) {
                const int qg = q0 + g*4 + r;
                const float v = sf[st][r] * 0.125f;
                sf[st][r] = (sg <= qg) ? v : -1e30f;
            }
        }
        // online softmax, per row r (16 lanes of a group hold one row's 16 cols)
        #pragma unroll
        for (int r = 0; r < 4; ++r) {
            float mx = fmaxf(sf[0][r], sf[1][r]);
            mx = fmaxf(mx, __shfl_xor(mx, 1));
            mx = fmaxf(mx, __shfl_xor(mx, 2));
            mx = fmaxf(mx, __shfl_xor(mx, 4));
            mx = fmaxf(mx, __shfl_xor(mx, 8));
            const float mnew = fmaxf(m4[r], mx);
            const float alpha = __expf(m4[r] - mnew);
            const float p0 = __expf(sf[0][r] - mnew);
            const float p1 = __expf(sf[1][r] - mnew);
            sf[0][r] = p0; sf[1][r] = p1;
            float sum = p0 + p1;
            sum += __shfl_xor(sum, 1);
            sum += __shfl_xor(sum, 2);
            sum += __shfl_xor(sum, 4);
            sum += __shfl_xor(sum, 8);
            l4[r] = l4[r] * alpha + sum;
            m4[r] = mnew;
            #pragma unroll
            for (int ni = 0; ni < 4; ++ni) acc[ni][r] *= alpha;
        }
        // P: C-layout -> A-layout via LDS
        __syncthreads();
        #pragma unroll
        for (int st = 0; st < 2; ++st)
            #pragma unroll
            for (int r = 0; r < 4; ++r)
                pl[(g*4 + r)*40 + st*16 + c] = f2bf(sf[st][r]);
        __syncthreads();
        const bf16x8 pa = *(const bf16x8*)(&pl[c*40 + g*8]);
        // PV: out(16x64) += P(16x32) V(32x64)
        #pragma unroll
        for (int ni = 0; ni < 4; ++ni) {
            bf16x8 vf;
            #pragma unroll
            for (int ii = 0; ii < 8; ++ii)
                vf[ii] = (short)Vb[(size_t)(kv0 + g*8 + ii) * HD_DIM + ni*16 + c];
            acc[ni] = __builtin_amdgcn_mfma_f32_16x16x32_bf16(pa, vf, acc[ni], 0, 0, 0);
        }
    }
    // epilogue: divide by l, write bf16 to [B*T, D] with head interleave
    const int b_ = bh >> 4, h = bh & 15;
    #pragma unroll
    for (int ni = 0; ni < 4; ++ni) {
        #pragma unroll
        for (int r = 0; r < 4; ++r) {
            const int qg = q0 + g*4 + r;
            const float o = acc[ni][r] / l4[r];
            O[(size_t)(b_*T_LEN + qg) * D_DIM + h*HD_DIM + ni*16 + c] = f2bf(o);
        }
    }
}

extern "C" void kernel_launch(void* const* d_in, const int* in_sizes, int n_in,
                              void* d_out, int out_size, void* d_ws, size_t ws_size,
                              hipStream_t stream)
{
    const float* x  = (const float*)d_in[0];
    const float* Wq = (const float*)d_in[1];
    const float* bq = (const float*)d_in[2];
    const float* Wk = (const float*)d_in[3];
    const float* bk = (const float*)d_in[4];
    const float* Wv = (const float*)d_in[5];
    const float* bv = (const float*)d_in[6];
    const float* Wo = (const float*)d_in[7];
    const float* bo = (const float*)d_in[8];
    float* out = (float*)d_out;

    char* ws = (char*)d_ws;
    const size_t MB = 1u << 20;
    unsigned short* xb  = (unsigned short*)(ws + 0*MB);   // 8 MB  [4096,1024]
    unsigned short* wqb = (unsigned short*)(ws + 8*MB);   // 2 MB
    unsigned short* wkb = (unsigned short*)(ws + 10*MB);  // 2 MB
    unsigned short* wvb = (unsigned short*)(ws + 12*MB);  // 2 MB
    unsigned short* wob = (unsigned short*)(ws + 14*MB);  // 2 MB
    unsigned short* qw  = (unsigned short*)(ws + 16*MB);  // 8 MB  [B,H,T,64]
    unsigned short* kw  = (unsigned short*)(ws + 24*MB);  // 8 MB
    unsigned short* vw  = (unsigned short*)(ws + 32*MB);  // 8 MB
    unsigned short* ow  = (unsigned short*)(ws + 40*MB);  // 8 MB  [B*T, 1024]

    cvt5<<<dim3(4096, 1, 5), dim3(256), 0, stream>>>(
        x, Wq, Wk, Wv, Wo, xb, wqb, wkb, wvb, wob,
        B_NUM*T_LEN*D_DIM, D_DIM*D_DIM, D_DIM*D_DIM, D_DIM*D_DIM, D_DIM*D_DIM);

    gemm_qkv<<<dim3((B_NUM*T_LEN)/128, D_DIM/128, 3), dim3(256), 0, stream>>>(
        xb, wqb, wkb, wvb, bq, bk, bv, qw, kw, vw);

    attn<<<dim3(B_NUM*H_NUM, T_LEN/16), dim3(64), 0, stream>>>(qw, kw, vw, ow);

    gemm_out<<<dim3((B_NUM*T_LEN)/128, D_DIM/128), dim3(256), 0, stream>>>(
        ow, wob, bo, out);
}